// Round 4
// baseline (3579.050 us; speedup 1.0000x reference)
//
#include <hip/hip_runtime.h>

#define NSTEPS 6

typedef unsigned short u16;
typedef unsigned int   u32;
typedef unsigned long long u64;
typedef __bf16 bf16x8 __attribute__((ext_vector_type(8)));
typedef float  f32x4  __attribute__((ext_vector_type(4)));

__device__ __forceinline__ u16 f2bf(float x) {
  union { float f; u32 u; } v; v.f = x;
  u32 r = v.u + 0x7FFFu + ((v.u >> 16) & 1u);
  return (u16)(r >> 16);
}
// tanh(x) = 1 - 2/(e^{2x}+1): mul, v_exp, add, rcp, fma ~5 ops; saturates correctly
__device__ __forceinline__ float ftanh(float x) {
  float e = __expf(2.f * x);
  return 1.f - 2.f / (e + 1.f);
}

// ---------------- prep kernels ----------------

// base1[j] = b1[j] + sum_c ctx[c] * W1[(65+c)*1024 + j]   (fold ctx into bias)
__global__ __launch_bounds__(256) void k_base1(
    const float* __restrict__ W1, const float* __restrict__ b1,
    const float* __restrict__ ctx, float* __restrict__ base1) {
  int j = blockIdx.x * 256 + threadIdx.x;
  float s = b1[j];
  for (int c = 0; c < 256; ++c)
    s += ctx[c] * W1[(size_t)(65 + c) * 1024 + j];
  base1[j] = s;
}

// Pack W[K][N] f32 -> P[nt][ks][lane][8] bf16 (MFMA B-fragment-linear).
// frag (nt,ks), lane: elems W[ks*32+(lane>>4)*8+j][nt*16+(lane&15)], j=0..7
__global__ __launch_bounds__(256) void k_pack(
    const float* __restrict__ W, u16* __restrict__ P, int ksl /*log2 KS*/, int N) {
  int gid = blockIdx.x * 256 + threadIdx.x;
  int lane = gid & 63, fid = gid >> 6;
  int ks = fid & ((1 << ksl) - 1);
  int nt = fid >> ksl;
  int n  = nt * 16 + (lane & 15);
  int k0 = ks * 32 + (lane >> 4) * 8;
  u16 v[8];
#pragma unroll
  for (int j = 0; j < 8; ++j) v[j] = f2bf(W[(size_t)(k0 + j) * N + n]);
  u64 lo = (u64)v[0] | ((u64)v[1] << 16) | ((u64)v[2] << 32) | ((u64)v[3] << 48);
  u64 hi = (u64)v[4] | ((u64)v[5] << 16) | ((u64)v[6] << 32) | ((u64)v[7] << 48);
  u64* dst = (u64*)(P + (size_t)gid * 8);
  dst[0] = lo; dst[1] = hi;
}

// ---------------- fused persistent ODE kernel ----------------
// Block = 32 samples, 8 waves (2M x 4N). All state in LDS; weights from L2
// as pre-packed fragments. 24 RK4 stages, no global intermediate traffic.

// one wave computes C rows [wm*16,+16) x cols [nw*256,+256) (16 n-tiles), K = KS*32
template<int KS>
__device__ __forceinline__ void gemm_nt16(
    const u16* __restrict__ Bp,   // pack base at this wave's first n-tile
    const u16* A, int arow, int rsu /*row stride bytes*/, int lane,
    f32x4 (&acc)[16]) {
  const int lk4 = lane >> 4;
  const int sx = arow & 7;
  const char* Ab = (const char*)A + arow * rsu;
  auto ldA = [&](int ks) -> bf16x8 {
    int slot = ks * 4 + lk4;
    return *(const bf16x8*)(Ab + ((slot ^ sx) << 4));
  };
  auto ldB = [&](int n, int ks) -> bf16x8 {
    return *(const bf16x8*)(Bp + ((size_t)(n * KS + ks) << 9) + (lane << 3));
  };
  bf16x8 A0, A1, B0[16], B1[16];
  A0 = ldA(0);
#pragma unroll
  for (int n = 0; n < 16; ++n) B0[n] = ldB(n, 0);
  A1 = ldA(1);
#pragma unroll
  for (int n = 0; n < 16; ++n) B1[n] = ldB(n, 1);
  for (int ks = 0; ks < KS - 2; ks += 2) {
#pragma unroll
    for (int n = 0; n < 16; ++n)
      acc[n] = __builtin_amdgcn_mfma_f32_16x16x32_bf16(A0, B0[n], acc[n], 0, 0, 0);
    A0 = ldA(ks + 2);
#pragma unroll
    for (int n = 0; n < 16; ++n) B0[n] = ldB(n, ks + 2);
#pragma unroll
    for (int n = 0; n < 16; ++n)
      acc[n] = __builtin_amdgcn_mfma_f32_16x16x32_bf16(A1, B1[n], acc[n], 0, 0, 0);
    A1 = ldA(ks + 3);
#pragma unroll
    for (int n = 0; n < 16; ++n) B1[n] = ldB(n, ks + 3);
  }
#pragma unroll
  for (int n = 0; n < 16; ++n)
    acc[n] = __builtin_amdgcn_mfma_f32_16x16x32_bf16(A0, B0[n], acc[n], 0, 0, 0);
#pragma unroll
  for (int n = 0; n < 16; ++n)
    acc[n] = __builtin_amdgcn_mfma_f32_16x16x32_bf16(A1, B1[n], acc[n], 0, 0, 0);
}

__global__ __launch_bounds__(512, 2) void k_fused(
    const float* __restrict__ theta0, const float* __restrict__ base1,
    const float* __restrict__ w1t,    // W1 row 64 (time row), f32
    const float* __restrict__ b2, const float* __restrict__ b3,
    const u16* __restrict__ P1, const u16* __restrict__ P2,
    const u16* __restrict__ P3, float* __restrict__ out) {
  __shared__ u16 h1s[32 * 1024];          // 64 KB, XOR-swizzled 16B slots
  __shared__ u16 h2s[32 * 1024];          // 64 KB
  __shared__ u16 xs[32 * 64];             // 4 KB
  __shared__ float th[2048], ac[2048], kvb[2048];  // 24 KB

  const int tid = threadIdx.x;
  const int wid = tid >> 6, lane = tid & 63;
  const int lrow = lane & 15, lk4 = lane >> 4;
  const int wm = wid >> 2, nw = wid & 3;
  const int arow = wm * 16 + lrow;
  const size_t r0 = (size_t)blockIdx.x * 32;

  *(f32x4*)&th[tid * 4] = *(const f32x4*)(theta0 + r0 * 64 + tid * 4);
  { f32x4 z = {0.f, 0.f, 0.f, 0.f}; *(f32x4*)&ac[tid * 4] = z; }
  __syncthreads();

  const float hs = 1.f / NSTEPS;

#pragma unroll 1
  for (int step = 0; step < NSTEPS; ++step) {
#pragma unroll 1
    for (int s = 0; s < 4; ++s) {
      // ---- U: acc += wg[s-1]*k ; x = theta + ah[s]*k (bf16, swizzled) ----
      {
        f32x4 t = *(f32x4*)&th[tid * 4];
        if (s > 0) {
          float wgp = (s == 1) ? hs / 6.f : hs / 3.f;
          float ahs = (s == 3) ? hs : 0.5f * hs;
          f32x4 k4 = *(f32x4*)&kvb[tid * 4];
          f32x4 a = *(f32x4*)&ac[tid * 4];
#pragma unroll
          for (int j = 0; j < 4; ++j) a[j] += wgp * k4[j];
          *(f32x4*)&ac[tid * 4] = a;
#pragma unroll
          for (int j = 0; j < 4; ++j) t[j] += ahs * k4[j];
        }
        int row = tid >> 4, d0 = (tid & 15) * 4;
        int slot = d0 >> 3;
        u64 pk = (u64)f2bf(t[0]) | ((u64)f2bf(t[1]) << 16) |
                 ((u64)f2bf(t[2]) << 32) | ((u64)f2bf(t[3]) << 48);
        *(u64*)((char*)xs + row * 128 + ((slot ^ (row & 7)) << 4) + (d0 & 7) * 2) = pk;
      }
      __syncthreads();
      float t_s = ((float)step + ((s == 0) ? 0.f : ((s == 3) ? 1.f : 0.5f))) * hs;

      // ---- layer1: h1 = tanh(x @ W1a + base1 + t*w1t), K=64 ----
      {
        f32x4 acc[16] = {};
        gemm_nt16<2>(P1 + ((size_t)(nw * 16) * 2) * 512, xs, arow, 128, lane, acc);
#pragma unroll
        for (int n = 0; n < 16; ++n) {
          int col = nw * 256 + n * 16 + lrow;
          float bb = base1[col] + t_s * w1t[col];
          int cslot = col >> 3;
#pragma unroll
          for (int q = 0; q < 4; ++q) {
            int r = wm * 16 + lk4 * 4 + q;
            *(u16*)((char*)h1s + r * 2048 + (((cslot) ^ (r & 7)) << 4) + (col & 7) * 2)
                = f2bf(ftanh(acc[n][q] + bb));
          }
        }
      }
      __syncthreads();

      // ---- layer2: h2 = tanh(h1 @ W2 + b2), K=1024 ----
      {
        f32x4 acc[16] = {};
        gemm_nt16<32>(P2 + ((size_t)(nw * 16) * 32) * 512, h1s, arow, 2048, lane, acc);
#pragma unroll
        for (int n = 0; n < 16; ++n) {
          int col = nw * 256 + n * 16 + lrow;
          float bb = b2[col];
          int cslot = col >> 3;
#pragma unroll
          for (int q = 0; q < 4; ++q) {
            int r = wm * 16 + lk4 * 4 + q;
            *(u16*)((char*)h2s + r * 2048 + (((cslot) ^ (r & 7)) << 4) + (col & 7) * 2)
                = f2bf(ftanh(acc[n][q] + bb));
          }
        }
      }
      __syncthreads();

      // ---- layer3: k = h2 @ W3 + b3, N=64 (wave tile 16x16, K=1024) ----
      {
        const u16* Bp = P3 + ((size_t)nw * 32) * 512;
        const char* Ab = (const char*)h2s + arow * 2048;
        const int sx = arow & 7;
        auto ldA = [&](int ks) -> bf16x8 {
          int slot = ks * 4 + lk4;
          return *(const bf16x8*)(Ab + ((slot ^ sx) << 4));
        };
        auto ldB = [&](int ks) -> bf16x8 {
          return *(const bf16x8*)(Bp + ((size_t)ks << 9) + (lane << 3));
        };
        f32x4 a3 = {};
        bf16x8 A0 = ldA(0), B0 = ldB(0), A1 = ldA(1), B1 = ldB(1);
        for (int ks = 0; ks < 30; ks += 2) {
          a3 = __builtin_amdgcn_mfma_f32_16x16x32_bf16(A0, B0, a3, 0, 0, 0);
          A0 = ldA(ks + 2); B0 = ldB(ks + 2);
          a3 = __builtin_amdgcn_mfma_f32_16x16x32_bf16(A1, B1, a3, 0, 0, 0);
          A1 = ldA(ks + 3); B1 = ldB(ks + 3);
        }
        a3 = __builtin_amdgcn_mfma_f32_16x16x32_bf16(A0, B0, a3, 0, 0, 0);
        a3 = __builtin_amdgcn_mfma_f32_16x16x32_bf16(A1, B1, a3, 0, 0, 0);
        int col = nw * 16 + lrow;
        float bb = b3[col];
#pragma unroll
        for (int q = 0; q < 4; ++q)
          kvb[(wm * 16 + lk4 * 4 + q) * 64 + col] = a3[q] + bb;
      }
      __syncthreads();
    }
    // ---- F: acc += h/6*k4 ; theta += acc ; acc = 0 ----
    {
      f32x4 k4 = *(f32x4*)&kvb[tid * 4];
      f32x4 a = *(f32x4*)&ac[tid * 4];
      f32x4 t = *(f32x4*)&th[tid * 4];
#pragma unroll
      for (int j = 0; j < 4; ++j) { a[j] += (hs / 6.f) * k4[j]; t[j] += a[j]; }
      *(f32x4*)&th[tid * 4] = t;
      f32x4 z = {0.f, 0.f, 0.f, 0.f}; *(f32x4*)&ac[tid * 4] = z;
    }
    __syncthreads();
  }
  *(f32x4*)(out + r0 * 64 + tid * 4) = *(f32x4*)&th[tid * 4];
}

// ---------------- host ----------------

extern "C" void kernel_launch(void* const* d_in, const int* in_sizes, int n_in,
                              void* d_out, int out_size, void* d_ws, size_t ws_size,
                              hipStream_t stream) {
  const float* theta0 = (const float*)d_in[0];
  const float* ctx    = (const float*)d_in[1];
  const float* W1     = (const float*)d_in[2];
  const float* b1     = (const float*)d_in[3];
  const float* W2     = (const float*)d_in[4];
  const float* b2     = (const float*)d_in[5];
  const float* W3     = (const float*)d_in[6];
  const float* b3     = (const float*)d_in[7];

  char* ws = (char*)d_ws;
  size_t o = 0;
  float* base1 = (float*)(ws + o); o += 4096;
  u16* P1 = (u16*)(ws + o); o += (size_t)64 * 1024 * 2;     // 128 KB  (K=64,N=1024)
  u16* P2 = (u16*)(ws + o); o += (size_t)1024 * 1024 * 2;   // 2 MB    (K=1024,N=1024)
  u16* P3 = (u16*)(ws + o); o += (size_t)1024 * 64 * 2;     // 128 KB  (K=1024,N=64)

  k_base1<<<dim3(4), 256, 0, stream>>>(W1, b1, ctx, base1);
  k_pack<<<dim3(32),  256, 0, stream>>>(W1, P1, 1, 1024);   // KS=2  (rows 0..63)
  k_pack<<<dim3(512), 256, 0, stream>>>(W2, P2, 5, 1024);   // KS=32
  k_pack<<<dim3(32),  256, 0, stream>>>(W3, P3, 5, 64);     // KS=32

  k_fused<<<dim3(256), 512, 0, stream>>>(theta0, base1, W1 + (size_t)64 * 1024,
                                         b2, b3, P1, P2, P3, (float*)d_out);
}

// Round 5
// 1384.847 us; speedup vs baseline: 2.5844x; 2.5844x over previous
//
#include <hip/hip_runtime.h>

#define NSTEPS 4

typedef unsigned short u16;
typedef unsigned int   u32;
typedef unsigned long long u64;
typedef __bf16 bf16x8 __attribute__((ext_vector_type(8)));
typedef float  f32x4  __attribute__((ext_vector_type(4)));

typedef __attribute__((address_space(1))) void gvoid_t;
typedef __attribute__((address_space(3))) void lvoid_t;

__device__ __forceinline__ void async_copy16(const void* g, void* l) {
  __builtin_amdgcn_global_load_lds((gvoid_t*)g, (lvoid_t*)l, 16, 0, 0);
}

__device__ __forceinline__ u16 f2bf(float x) {
  union { float f; u32 u; } v; v.f = x;
  u32 r = v.u + 0x7FFFu + ((v.u >> 16) & 1u);
  return (u16)(r >> 16);
}
__device__ __forceinline__ float ftanh(float x) {
  float e = __expf(2.f * x);
  return 1.f - 2.f / (e + 1.f);
}

// ---------------- prep kernels ----------------

// out[C][R] = bf16(in[R][C])
__global__ __launch_bounds__(256) void k_transpose_cast(
    const float* __restrict__ in, u16* __restrict__ out, int R, int C) {
  __shared__ float t[64][65];
  int tr = blockIdx.x * 64, tc = blockIdx.y * 64;
  int lr = threadIdx.x >> 6;
  int lc = threadIdx.x & 63;
#pragma unroll
  for (int i = 0; i < 16; ++i) {
    int r = i * 4 + lr;
    int gr = tr + r, gc = tc + lc;
    t[r][lc] = (gr < R && gc < C) ? in[(size_t)gr * C + gc] : 0.f;
  }
  __syncthreads();
#pragma unroll
  for (int i = 0; i < 16; ++i) {
    int c = i * 4 + lr;
    int gc = tc + c, gr = tr + lc;
    if (gc < C && gr < R) out[(size_t)gc * R + gr] = f2bf(t[lc][c]);
  }
}

// base1[j] = b1[j] + sum_c ctx[c] * W1[(65+c)*1024 + j]
__global__ __launch_bounds__(256) void k_base1(
    const float* __restrict__ W1, const float* __restrict__ b1,
    const float* __restrict__ ctx, float* __restrict__ base1) {
  int j = blockIdx.x * 256 + threadIdx.x;
  float s = b1[j];
  for (int c = 0; c < 256; ++c)
    s += ctx[c] * W1[(size_t)(65 + c) * 1024 + j];
  base1[j] = s;
}

// Pack W[K][N] f32 -> B-fragment-linear bf16: frag fid=(nt*KS+ks), lane:
// elems W[ks*32+(lane>>4)*8+j][nt*16+(lane&15)]
__global__ __launch_bounds__(256) void k_pack(
    const float* __restrict__ W, u16* __restrict__ P, int ksl, int N) {
  int gid = blockIdx.x * 256 + threadIdx.x;
  int lane = gid & 63, fid = gid >> 6;
  int ks = fid & ((1 << ksl) - 1);
  int nt = fid >> ksl;
  int n  = nt * 16 + (lane & 15);
  int k0 = ks * 32 + (lane >> 4) * 8;
  u16 v[8];
#pragma unroll
  for (int j = 0; j < 8; ++j) v[j] = f2bf(W[(size_t)(k0 + j) * N + n]);
  u64 lo = (u64)v[0] | ((u64)v[1] << 16) | ((u64)v[2] << 32) | ((u64)v[3] << 48);
  u64 hi = (u64)v[4] | ((u64)v[5] << 16) | ((u64)v[6] << 32) | ((u64)v[7] << 48);
  u64* dst = (u64*)(P + (size_t)gid * 8);
  dst[0] = lo; dst[1] = hi;
}

// ---------------- fused layer1+layer2 ----------------
// h2[8192,1024] = tanh( tanh(x @ W1a + base1 + t*w1t) @ W2 + b2 ), x formed
// in prologue. h1 never hits global: per K-step a mini-GEMM (K=64) builds
// the 128x64 h1 tile in LDS (dbuf) feeding the main GEMM's A side.
__global__ __launch_bounds__(512, 3) void k_fwd(
    const float* __restrict__ theta, const float* __restrict__ kbuf,
    const u16* __restrict__ P1, const float* __restrict__ base1,
    const float* __restrict__ w1t, const u16* __restrict__ W2T,
    const float* __restrict__ b2, u16* __restrict__ h2,
    float a_h, float t_s, int use_k) {
  __shared__ u16 xs[128 * 64];        // 16 KB, swizzled
  __shared__ u16 h1b[2][128 * 64];    // 32 KB
  __shared__ u16 Bb[2][128 * 64];     // 32 KB
  const int tid = threadIdx.x, wid = tid >> 6, lane = tid & 63;
  const int brow = blockIdx.x * 128, bcol = blockIdx.y * 128;
  const int wm = wid >> 2, wn = wid & 3;   // main: 2M x 4N (wave tile 64x32)
  const int lrow = lane & 15, lk4 = lane >> 4;

  // ---- prologue: x = theta (+ a_h*k) -> bf16, swizzled into xs ----
  {
    int row = tid >> 2;             // 0..127
    int sp = (tid & 3) * 2;         // slot pair
#pragma unroll
    for (int p = 0; p < 2; ++p) {
      int slot = sp + p;
      int g = (brow + row) * 64 + slot * 8;
      f32x4 t0 = *(const f32x4*)(theta + g);
      f32x4 t1 = *(const f32x4*)(theta + g + 4);
      if (use_k) {
        f32x4 k0 = *(const f32x4*)(kbuf + g);
        f32x4 k1 = *(const f32x4*)(kbuf + g + 4);
#pragma unroll
        for (int j = 0; j < 4; ++j) { t0[j] += a_h * k0[j]; t1[j] += a_h * k1[j]; }
      }
      u64 lo = (u64)f2bf(t0[0]) | ((u64)f2bf(t0[1]) << 16) |
               ((u64)f2bf(t0[2]) << 32) | ((u64)f2bf(t0[3]) << 48);
      u64 hi = (u64)f2bf(t1[0]) | ((u64)f2bf(t1[1]) << 16) |
               ((u64)f2bf(t1[2]) << 32) | ((u64)f2bf(t1[3]) << 48);
      u64* dst = (u64*)((char*)xs + row * 128 + ((slot ^ (row & 7)) << 4));
      dst[0] = lo; dst[1] = hi;
    }
  }

  auto stageB = [&](int buf, int k0) {
#pragma unroll
    for (int i = 0; i < 2; ++i) {
      int row = i * 64 + (tid >> 3);
      int ksl = (tid & 7) ^ (row & 7);
      async_copy16((const char*)W2T + ((size_t)(bcol + row) * 1024 + k0 + ksl * 8) * 2,
                   (char*)&Bb[buf][0] + i * 8192 + tid * 16);
    }
  };

  // mini-GEMM: h1 tile t (cols j0=t*64..+64) -> h1b[buf]
  auto mini = [&](int buf, int t) {
    int j0 = t * 64;
    f32x4 macc[4] = {};
    const int ar = wid * 16 + lrow;
    const char* Axb = (const char*)xs + ar * 128;
    const int sxm = ar & 7;
#pragma unroll
    for (int ks = 0; ks < 2; ++ks) {
      bf16x8 a = *(const bf16x8*)(Axb + (((ks * 4 + lk4) ^ sxm) << 4));
#pragma unroll
      for (int n = 0; n < 4; ++n) {
        bf16x8 b = *(const bf16x8*)(P1 + ((size_t)((t * 4 + n) * 2 + ks) << 9) + lane * 8);
        macc[n] = __builtin_amdgcn_mfma_f32_16x16x32_bf16(a, b, macc[n], 0, 0, 0);
      }
    }
#pragma unroll
    for (int n = 0; n < 4; ++n) {
      int c = n * 16 + lrow;
      float bb = base1[j0 + c] + t_s * w1t[j0 + c];
      int cslot = c >> 3;
#pragma unroll
      for (int q = 0; q < 4; ++q) {
        int r = wid * 16 + lk4 * 4 + q;
        *(u16*)((char*)&h1b[buf][0] + r * 128 + ((cslot ^ (r & 7)) << 4) + (c & 7) * 2)
            = f2bf(ftanh(macc[n][q] + bb));
      }
    }
  };

  stageB(0, 0);
  __syncthreads();          // xs visible, B(0) landed
  mini(0, 0);
  __syncthreads();          // h1b[0] visible

  f32x4 acc[4][2] = {};
  int cur = 0;
  for (int t = 0; t < 16; ++t) {
    if (t < 15) { stageB(cur ^ 1, (t + 1) * 64); mini(cur ^ 1, t + 1); }
#pragma unroll
    for (int kk = 0; kk < 2; ++kk) {
      bf16x8 a[4], b[2];
#pragma unroll
      for (int m = 0; m < 4; ++m) {
        int row = wm * 64 + m * 16 + lrow;
        a[m] = *(const bf16x8*)((const char*)&h1b[cur][0] + row * 128 +
                                (((kk * 4 + lk4) ^ (row & 7)) << 4));
      }
#pragma unroll
      for (int n = 0; n < 2; ++n) {
        int row = wn * 32 + n * 16 + lrow;
        b[n] = *(const bf16x8*)((const char*)&Bb[cur][0] + row * 128 +
                                (((kk * 4 + lk4) ^ (row & 7)) << 4));
      }
#pragma unroll
      for (int m = 0; m < 4; ++m)
#pragma unroll
        for (int n = 0; n < 2; ++n)
          acc[m][n] = __builtin_amdgcn_mfma_f32_16x16x32_bf16(a[m], b[n], acc[m][n], 0, 0, 0);
    }
    __syncthreads();
    cur ^= 1;
  }
#pragma unroll
  for (int n = 0; n < 2; ++n) {
    int col = bcol + wn * 32 + n * 16 + lrow;
    float bb = b2[col];
#pragma unroll
    for (int m = 0; m < 4; ++m) {
      int row0 = brow + wm * 64 + m * 16 + lk4 * 4;
#pragma unroll
      for (int q = 0; q < 4; ++q)
        h2[(size_t)(row0 + q) * 1024 + col] = f2bf(ftanh(acc[m][n][q] + bb));
    }
  }
}

// ---------------- fused layer3 + RK update ----------------
// k = h2 @ W3 + b3 (N=64); then acc += w*k (and theta += acc at finalize).
__global__ __launch_bounds__(256) void k_bwd(
    const u16* __restrict__ h2, const u16* __restrict__ P3,
    const float* __restrict__ b3, float* __restrict__ kbuf,
    float* __restrict__ acb, float* __restrict__ theta,
    float wgt, int finalize) {
  __shared__ u16 Ab[2][32 * 64];    // 2 x 4 KB
  const int tid = threadIdx.x, wid = tid >> 6, lane = tid & 63;
  const int brow = blockIdx.x * 32;
  const int wm = wid >> 1, wn = wid & 1;   // 2M x 2N (wave tile 16x32)
  const int lrow = lane & 15, lk4 = lane >> 4;

  auto stageA = [&](int buf, int k0) {
    int row = tid >> 3;
    int ksl = (tid & 7) ^ (row & 7);
    async_copy16((const char*)h2 + ((size_t)(brow + row) * 1024 + k0 + ksl * 8) * 2,
                 (char*)&Ab[buf][0] + tid * 16);
  };

  stageA(0, 0);
  __syncthreads();
  f32x4 acc[2] = {};
  int cur = 0;
  const int arow = wm * 16 + lrow;
  const int sxm = arow & 7;
  for (int t = 0; t < 16; ++t) {
    if (t < 15) stageA(cur ^ 1, (t + 1) * 64);
#pragma unroll
    for (int kk = 0; kk < 2; ++kk) {
      bf16x8 a = *(const bf16x8*)((const char*)&Ab[cur][0] + arow * 128 +
                                  (((kk * 4 + lk4) ^ sxm) << 4));
      int ksg = t * 2 + kk;
#pragma unroll
      for (int n = 0; n < 2; ++n) {
        bf16x8 b = *(const bf16x8*)(P3 + ((size_t)((wn * 2 + n) * 32 + ksg) << 9) + lane * 8);
        acc[n] = __builtin_amdgcn_mfma_f32_16x16x32_bf16(a, b, acc[n], 0, 0, 0);
      }
    }
    __syncthreads();
    cur ^= 1;
  }
#pragma unroll
  for (int n = 0; n < 2; ++n) {
    int c = wn * 32 + n * 16 + lrow;
    float kb = b3[c];
#pragma unroll
    for (int q = 0; q < 4; ++q) {
      int r = brow + wm * 16 + lk4 * 4 + q;
      int idx = r * 64 + c;
      float kv = acc[n][q] + kb;
      if (finalize) { theta[idx] += acb[idx] + wgt * kv; acb[idx] = 0.f; }
      else          { kbuf[idx] = kv; acb[idx] += wgt * kv; }
    }
  }
}

// ---------------- host ----------------

extern "C" void kernel_launch(void* const* d_in, const int* in_sizes, int n_in,
                              void* d_out, int out_size, void* d_ws, size_t ws_size,
                              hipStream_t stream) {
  const float* theta0 = (const float*)d_in[0];
  const float* ctx    = (const float*)d_in[1];
  const float* W1     = (const float*)d_in[2];
  const float* b1     = (const float*)d_in[3];
  const float* W2     = (const float*)d_in[4];
  const float* b2     = (const float*)d_in[5];
  const float* W3     = (const float*)d_in[6];
  const float* b3     = (const float*)d_in[7];

  char* ws = (char*)d_ws;
  size_t o = 0;
  float* th    = (float*)(ws + o); o += (size_t)8192 * 64 * 4;   // 2 MB
  float* acb   = (float*)(ws + o); o += (size_t)8192 * 64 * 4;   // 2 MB
  float* kbuf  = (float*)(ws + o); o += (size_t)8192 * 64 * 4;   // 2 MB
  float* base1 = (float*)(ws + o); o += 4096;
  u16* W2T = (u16*)(ws + o); o += (size_t)1024 * 1024 * 2;       // 2 MB
  u16* P1  = (u16*)(ws + o); o += (size_t)64 * 1024 * 2;         // 128 KB
  u16* P3  = (u16*)(ws + o); o += (size_t)1024 * 64 * 2;         // 128 KB
  u16* h2  = (u16*)(ws + o); o += (size_t)8192 * 1024 * 2;       // 16 MB

  hipMemcpyAsync(th, theta0, (size_t)8192 * 64 * 4, hipMemcpyDeviceToDevice, stream);
  hipMemsetAsync(acb, 0, (size_t)8192 * 64 * 4, stream);

  k_base1<<<dim3(4), 256, 0, stream>>>(W1, b1, ctx, base1);
  k_transpose_cast<<<dim3(16, 16), 256, 0, stream>>>(W2, W2T, 1024, 1024);
  k_pack<<<dim3(32), 256, 0, stream>>>(W1, P1, 1, 1024);   // KS=2  (theta rows)
  k_pack<<<dim3(32), 256, 0, stream>>>(W3, P3, 5, 64);     // KS=32

  const float hs = 1.f / NSTEPS;
  const float ah[4] = {0.f, 0.5f * hs, 0.5f * hs, hs};
  const float ct[4] = {0.f, 0.5f, 0.5f, 1.f};
  const float wg[4] = {hs / 6.f, hs / 3.f, hs / 3.f, hs / 6.f};

  for (int step = 0; step < NSTEPS; ++step) {
    float tn = (float)step * hs;
    for (int s = 0; s < 4; ++s) {
      k_fwd<<<dim3(64, 8), 512, 0, stream>>>(th, kbuf, P1, base1,
                                             W1 + (size_t)64 * 1024, W2T, b2, h2,
                                             ah[s], tn + ct[s] * hs, s > 0 ? 1 : 0);
      k_bwd<<<dim3(256), 256, 0, stream>>>(h2, P3, b3, kbuf, acb, th,
                                           wg[s], s == 3 ? 1 : 0);
    }
  }
  hipMemcpyAsync(d_out, th, (size_t)8192 * 64 * 4, hipMemcpyDeviceToDevice, stream);
}

// Round 6
// 872.809 us; speedup vs baseline: 4.1006x; 1.5867x over previous
//
#include <hip/hip_runtime.h>

#define NSTEPS 4

typedef unsigned short u16;
typedef unsigned int   u32;
typedef unsigned long long u64;
typedef __bf16 bf16x8 __attribute__((ext_vector_type(8)));
typedef float  f32x4  __attribute__((ext_vector_type(4)));

typedef __attribute__((address_space(1))) void gvoid_t;
typedef __attribute__((address_space(3))) void lvoid_t;

__device__ __forceinline__ void async_copy16(const void* g, void* l) {
  __builtin_amdgcn_global_load_lds((gvoid_t*)g, (lvoid_t*)l, 16, 0, 0);
}

__device__ __forceinline__ u16 bfc(float x) {
  union { __bf16 b; u16 u; } v; v.b = (__bf16)x; return v.u;
}
__device__ __forceinline__ float ftanh(float x) {
  float e = __expf(2.f * x);
  return 1.f - 2.f / (e + 1.f);
}

// ---------------- prep kernels ----------------

// out[C][R] = bf16(in[R][C])
__global__ __launch_bounds__(256) void k_transpose_cast(
    const float* __restrict__ in, u16* __restrict__ out, int R, int C) {
  __shared__ float t[64][65];
  int tr = blockIdx.x * 64, tc = blockIdx.y * 64;
  int lr = threadIdx.x >> 6;
  int lc = threadIdx.x & 63;
#pragma unroll
  for (int i = 0; i < 16; ++i) {
    int r = i * 4 + lr;
    int gr = tr + r, gc = tc + lc;
    t[r][lc] = (gr < R && gc < C) ? in[(size_t)gr * C + gc] : 0.f;
  }
  __syncthreads();
#pragma unroll
  for (int i = 0; i < 16; ++i) {
    int c = i * 4 + lr;
    int gc = tc + c, gr = tr + lc;
    if (gc < C && gr < R) out[(size_t)gc * R + gr] = bfc(t[lc][c]);
  }
}

// base1[j] = b1[j] + sum_c ctx[c] * W1[(65+c)*1024 + j]
__global__ __launch_bounds__(256) void k_base1(
    const float* __restrict__ W1, const float* __restrict__ b1,
    const float* __restrict__ ctx, float* __restrict__ base1) {
  int j = blockIdx.x * 256 + threadIdx.x;
  float s = b1[j];
  for (int c = 0; c < 256; ++c)
    s += ctx[c] * W1[(size_t)(65 + c) * 1024 + j];
  base1[j] = s;
}

// Pack W[K][N] f32 -> B-fragment-linear bf16: fid = nt*KS + ks, lane holds
// W[ks*32+(lane>>4)*8+j][nt*16+(lane&15)], j=0..7
__global__ __launch_bounds__(256) void k_pack(
    const float* __restrict__ W, u16* __restrict__ P, int ksl, int N) {
  int gid = blockIdx.x * 256 + threadIdx.x;
  int lane = gid & 63, fid = gid >> 6;
  int ks = fid & ((1 << ksl) - 1);
  int nt = fid >> ksl;
  int n  = nt * 16 + (lane & 15);
  int k0 = ks * 32 + (lane >> 4) * 8;
  u16 v[8];
#pragma unroll
  for (int j = 0; j < 8; ++j) v[j] = bfc(W[(size_t)(k0 + j) * N + n]);
  u64 lo = (u64)v[0] | ((u64)v[1] << 16) | ((u64)v[2] << 32) | ((u64)v[3] << 48);
  u64 hi = (u64)v[4] | ((u64)v[5] << 16) | ((u64)v[6] << 32) | ((u64)v[7] << 48);
  u64* dst = (u64*)(P + (size_t)gid * 8);
  dst[0] = lo; dst[1] = hi;
}

// ---------------- fused L1+L2+L3-partial ----------------
// Block: 64 sample rows x 256 h2 cols (grid 128 x 4), 512 threads (8 waves).
// Per K-step (BK=32): mini-GEMM builds h1 tile [64x32] in LDS (dbuf) from
// xs + packed W1 frags; main GEMM accumulates h2. Epilogue: tanh(h2) into
// LDS (reusing B buffers), then L3 partial vs packed W3 -> kpart slice.
__global__ __launch_bounds__(512, 4) void k_fwd(
    const float* __restrict__ theta, const float* __restrict__ kbuf,
    const u16* __restrict__ P1, const float* __restrict__ base1,
    const float* __restrict__ w1t, const u16* __restrict__ W2T,
    const float* __restrict__ b2, const u16* __restrict__ P3,
    float* __restrict__ kpart, float a_h, float t_s, int use_k) {
  __shared__ u16 xs[64 * 64];        // 8 KB, 128B rows, slot^= row&7
  __shared__ u16 h1b[2][64 * 32];    // 2 x 4 KB, row-pairs packed to 128B
  __shared__ u16 Bb[2][256 * 32];    // 2 x 16 KB, row-pairs; reused as h2L[64][256]
  const int tid = threadIdx.x, wid = tid >> 6, lane = tid & 63;
  const int lrow = lane & 15, lk4 = lane >> 4;
  const int brow = blockIdx.x * 64;
  const int bcol = blockIdx.y * 256;
  const int wm = wid >> 2, wn = wid & 3;    // main: 2M x 4N (wave tile 32x64)
  const int wm2 = wid >> 1, wn2 = wid & 1;  // mini/L3: 4M x 2N

  // ---- prologue: xs = bf16(theta + a_h*k), swizzled ----
  {
    int row = tid >> 3, sl = tid & 7;
    int g = (brow + row) * 64 + sl * 8;
    f32x4 t0 = *(const f32x4*)(theta + g);
    f32x4 t1 = *(const f32x4*)(theta + g + 4);
    if (use_k) {
      f32x4 k0 = *(const f32x4*)(kbuf + g);
      f32x4 k1 = *(const f32x4*)(kbuf + g + 4);
#pragma unroll
      for (int j = 0; j < 4; ++j) { t0[j] += a_h * k0[j]; t1[j] += a_h * k1[j]; }
    }
    bf16x8 v;
#pragma unroll
    for (int j = 0; j < 4; ++j) { v[j] = (__bf16)t0[j]; v[4 + j] = (__bf16)t1[j]; }
    *(bf16x8*)((char*)xs + row * 128 + ((sl ^ (row & 7)) << 4)) = v;
  }

  // stage W2T slice for K-step at k0 into Bb[buf] (pre-swizzled source)
  auto stageB = [&](int buf, int k0) {
#pragma unroll
    for (int i = 0; i < 2; ++i) {
      int sl = i * 512 + tid;           // 0..1023 LDS 16B slots
      int pr = sl >> 3;
      int s8u = (sl & 7) ^ (pr & 7);
      int n = pr * 2 + (s8u >> 2);
      int kq = s8u & 3;
      async_copy16((const char*)W2T + ((size_t)(bcol + n) * 1024 + k0 + kq * 8) * 2,
                   (char*)&Bb[buf][0] + i * 8192 + tid * 16);
    }
  };

  // mini-GEMM: h1 tile for K-step t (h1 cols t*32..+32) -> h1b[buf]
  auto mini = [&](int buf, int t) {
    f32x4 macc = {0.f, 0.f, 0.f, 0.f};
    const int xr = wm2 * 16 + lrow;
    const char* Axb = (const char*)xs + xr * 128;
    const int sx = xr & 7;
    const int ntg = t * 2 + wn2;
#pragma unroll
    for (int ks = 0; ks < 2; ++ks) {
      bf16x8 a = *(const bf16x8*)(Axb + (((ks * 4 + lk4) ^ sx) << 4));
      bf16x8 b = *(const bf16x8*)(P1 + ((size_t)(ntg * 2 + ks) << 9) + lane * 8);
      macc = __builtin_amdgcn_mfma_f32_16x16x32_bf16(a, b, macc, 0, 0, 0);
    }
    int cc = wn2 * 16 + lrow;           // col within 0..31
    int colg = t * 32 + cc;
    float bb = base1[colg] + t_s * w1t[colg];
    int kq = cc >> 3;
#pragma unroll
    for (int q = 0; q < 4; ++q) {
      int r = wm2 * 16 + lk4 * 4 + q;
      int pr = r >> 1;
      int s8 = ((r & 1) * 4 + kq) ^ (pr & 7);
      *(u16*)((char*)&h1b[buf][0] + pr * 128 + (s8 << 4) + (cc & 7) * 2)
          = bfc(ftanh(macc[q] + bb));
    }
  };

  stageB(0, 0);
  __syncthreads();      // xs + Bb[0] ready
  mini(0, 0);
  __syncthreads();      // h1b[0] ready

  f32x4 acc[2][4] = {};
  int cur = 0;
  for (int t = 0; t < 32; ++t) {
    if (t < 31) { stageB(cur ^ 1, (t + 1) * 32); mini(cur ^ 1, t + 1); }
    bf16x8 a[2], b[4];
#pragma unroll
    for (int m = 0; m < 2; ++m) {
      int ar = wm * 32 + m * 16 + lrow;
      int pr = ar >> 1;
      a[m] = *(const bf16x8*)((const char*)&h1b[cur][0] + pr * 128 +
                              ((((ar & 1) * 4 + lk4) ^ (pr & 7)) << 4));
    }
#pragma unroll
    for (int n = 0; n < 4; ++n) {
      int bn = wn * 64 + n * 16 + lrow;
      int pr = bn >> 1;
      b[n] = *(const bf16x8*)((const char*)&Bb[cur][0] + pr * 128 +
                              ((((bn & 1) * 4 + lk4) ^ (pr & 7)) << 4));
    }
#pragma unroll
    for (int m = 0; m < 2; ++m)
#pragma unroll
      for (int n = 0; n < 4; ++n)
        acc[m][n] = __builtin_amdgcn_mfma_f32_16x16x32_bf16(a[m], b[n], acc[m][n], 0, 0, 0);
    __syncthreads();
    cur ^= 1;
  }

  // ---- h2 tile: tanh -> LDS (reuse Bb as h2L[64][256], 512B rows) ----
  u16* h2L = (u16*)&Bb[0][0];
#pragma unroll
  for (int m = 0; m < 2; ++m)
#pragma unroll
    for (int n = 0; n < 4; ++n) {
      int cc = wn * 64 + n * 16 + lrow;
      float bb = b2[bcol + cc];
      int slu = cc >> 3;
#pragma unroll
      for (int q = 0; q < 4; ++q) {
        int rr = wm * 32 + m * 16 + lk4 * 4 + q;
        int sl = (slu & 24) | ((slu & 7) ^ (rr & 7));
        *(u16*)((char*)h2L + rr * 512 + (sl << 4) + (cc & 7) * 2)
            = bfc(ftanh(acc[m][n][q] + bb));
      }
    }
  __syncthreads();

  // ---- L3 partial: kpart[y] = h2L @ W3[bcol..bcol+256, :] ----
  {
    f32x4 a3[2] = {{}, {}};
    const int ar3 = wm2 * 16 + lrow;
    const char* Ab3 = (const char*)h2L + ar3 * 512;
    const int sx3 = ar3 & 7;
#pragma unroll
    for (int ks = 0; ks < 8; ++ks) {
      int slu = ks * 4 + lk4;
      bf16x8 a = *(const bf16x8*)(Ab3 + (((slu & 24) | ((slu & 7) ^ sx3)) << 4));
#pragma unroll
      for (int n = 0; n < 2; ++n) {
        int fid = (wn2 * 2 + n) * 32 + blockIdx.y * 8 + ks;
        bf16x8 b = *(const bf16x8*)(P3 + ((size_t)fid << 9) + lane * 8);
        a3[n] = __builtin_amdgcn_mfma_f32_16x16x32_bf16(a, b, a3[n], 0, 0, 0);
      }
    }
    float* kp = kpart + (size_t)blockIdx.y * 8192 * 64;
#pragma unroll
    for (int n = 0; n < 2; ++n) {
      int cc = wn2 * 32 + n * 16 + lrow;
#pragma unroll
      for (int q = 0; q < 4; ++q) {
        int rr = brow + wm2 * 16 + lk4 * 4 + q;
        kp[(size_t)rr * 64 + cc] = a3[n][q];
      }
    }
  }
}

// k = sum(kpart) + b3 ; acc += w*k ; finalize: theta += acc, acc = 0
__global__ __launch_bounds__(256) void k_update(
    const float* __restrict__ kpart, const float* __restrict__ b3,
    float* __restrict__ kbuf, float* __restrict__ acb, float* __restrict__ theta,
    float wgt, int finalize) {
  int i = blockIdx.x * 256 + threadIdx.x;
  const int N = 8192 * 64;
  float kv = kpart[i] + kpart[N + i] + kpart[2 * N + i] + kpart[3 * N + i] + b3[i & 63];
  float a = acb[i] + wgt * kv;
  if (finalize) { theta[i] += a; acb[i] = 0.f; }
  else          { kbuf[i] = kv; acb[i] = a; }
}

// ---------------- host ----------------

extern "C" void kernel_launch(void* const* d_in, const int* in_sizes, int n_in,
                              void* d_out, int out_size, void* d_ws, size_t ws_size,
                              hipStream_t stream) {
  const float* theta0 = (const float*)d_in[0];
  const float* ctx    = (const float*)d_in[1];
  const float* W1     = (const float*)d_in[2];
  const float* b1     = (const float*)d_in[3];
  const float* W2     = (const float*)d_in[4];
  const float* b2     = (const float*)d_in[5];
  const float* W3     = (const float*)d_in[6];
  const float* b3     = (const float*)d_in[7];

  char* ws = (char*)d_ws;
  size_t o = 0;
  float* th    = (float*)(ws + o); o += (size_t)8192 * 64 * 4;       // 2 MB
  float* acb   = (float*)(ws + o); o += (size_t)8192 * 64 * 4;       // 2 MB
  float* kbuf  = (float*)(ws + o); o += (size_t)8192 * 64 * 4;       // 2 MB
  float* base1 = (float*)(ws + o); o += 4096;
  u16* W2T = (u16*)(ws + o); o += (size_t)1024 * 1024 * 2;           // 2 MB
  u16* P1  = (u16*)(ws + o); o += (size_t)64 * 1024 * 2;             // 128 KB
  u16* P3  = (u16*)(ws + o); o += (size_t)1024 * 64 * 2;             // 128 KB
  float* kpart = (float*)(ws + o); o += (size_t)4 * 8192 * 64 * 4;   // 8 MB

  hipMemcpyAsync(th, theta0, (size_t)8192 * 64 * 4, hipMemcpyDeviceToDevice, stream);
  hipMemsetAsync(acb, 0, (size_t)8192 * 64 * 4, stream);

  k_base1<<<dim3(4), 256, 0, stream>>>(W1, b1, ctx, base1);
  k_transpose_cast<<<dim3(16, 16), 256, 0, stream>>>(W2, W2T, 1024, 1024);
  k_pack<<<dim3(32), 256, 0, stream>>>(W1, P1, 1, 1024);   // 64x2 frags (theta rows)
  k_pack<<<dim3(32), 256, 0, stream>>>(W3, P3, 5, 64);     // 4x32 frags

  const float hs = 1.f / NSTEPS;
  const float ah[4] = {0.f, 0.5f * hs, 0.5f * hs, hs};
  const float ct[4] = {0.f, 0.5f, 0.5f, 1.f};
  const float wg[4] = {hs / 6.f, hs / 3.f, hs / 3.f, hs / 6.f};

  for (int step = 0; step < NSTEPS; ++step) {
    float tn = (float)step * hs;
    for (int s = 0; s < 4; ++s) {
      k_fwd<<<dim3(128, 4), 512, 0, stream>>>(th, kbuf, P1, base1,
                                              W1 + (size_t)64 * 1024, W2T, b2,
                                              P3, kpart,
                                              ah[s], tn + ct[s] * hs, s > 0 ? 1 : 0);
      k_update<<<dim3(2048), 256, 0, stream>>>(kpart, b3, kbuf, acb, th,
                                               wg[s], s == 3 ? 1 : 0);
    }
  }
  hipMemcpyAsync(d_out, th, (size_t)8192 * 64 * 4, hipMemcpyDeviceToDevice, stream);
}